// Round 19
// baseline (1047.690 us; speedup 1.0000x reference)
//
#include <hip/hip_runtime.h>
#include <hip/hip_bf16.h>

typedef __hip_bfloat16 bf16;

#define BATCH 128
#define SEQ   200
#define NUMQ  1000
#define DD    64
#define MM    50
#define MH    25     // m-half
#define CHUNKS 10
#define CLEN   20    // SEQ / CHUNKS
#define RPB   16

// Budget pinned by r16/r18 measurements: K2 body ~72us (near per-CU store floor),
// K1+K3 bodies ~50us, gaps ~8us, fixed overhead ~14us. This round: K1 eliminated
// (phase 0 inside the scan kernel, w/e/a in regs+LDS, no ws round-trip); K3 at
// 256 blocks staging Wf once. grid.sync (r18) rejected: ~100us for 2 syncs.

__device__ __forceinline__ float rdlane(float v, int j) {
    return __uint_as_float(__builtin_amdgcn_readlane(__float_as_uint(v), j));
}

// ---------------- K2': phase0 (own 20 rows' w/e/a, reg/LDS) + r15 scan ----------------
// grid 256 (b,h) x 640 thr. LDS: POOL 64KB (weights aliased in phase 0) +
// RBUF 5KB + WL 20KB = 89.1KB -> 1 block/CU (grid == CU count).
__global__ __launch_bounds__(640) void k2_fused0(
    const int* __restrict__ q_, const int* __restrict__ r_,
    const float* __restrict__ k_emb, const float* __restrict__ v_emb,
    const float* __restrict__ Mk, const float* __restrict__ Mv0,
    const float* __restrict__ We, const float* __restrict__ be,
    const float* __restrict__ Wa, const float* __restrict__ ba,
    float* __restrict__ read2_buf, float* __restrict__ out_Mv)
{
    __shared__ float POOL[16000];          // phase0: weights; phase2+: S + staging
    __shared__ float RBUF[CHUNKS][128];    // per-wave k/v row
    __shared__ float WL[CHUNKS][CLEN][MH]; // per-wave own-half w coefficients

    const int blk  = blockIdx.x;
    const int b    = blk >> 1;
    const int h    = blk & 1;
    const int tid  = threadIdx.x;
    const int wv   = tid >> 6;      // chunk 0..9
    const int lane = tid & 63;
    const int t0   = wv * CLEN;
    const int mb   = h * MH;

    float* Mk_l = POOL;             // [50][65]  (dead after phase 0)
    float* We_l = POOL + 3250;      // [64][64]
    float* Wa_l = POOL + 7346;      // [64][64]

    for (int i = tid; i < MM * DD; i += 640) Mk_l[(i >> 6) * 65 + (i & 63)] = Mk[i];
    for (int i = tid; i < DD * DD; i += 640) { We_l[i] = We[i]; Wa_l[i] = Wa[i]; }
    const float be_l = be[lane];
    const float ba_l = ba[lane];
    __syncthreads();

    // ---- phase 0: this wave's 20 rows of w/e/a + affine chunk summary ----
    float A[MH], B[MH], e20[CLEN], a20[CLEN];
    #pragma unroll
    for (int j = 0; j < MH; ++j) { A[j] = 1.f; B[j] = 0.f; }

    float* kv = RBUF[wv];
    {
        int qi = min(max(q_[b * SEQ + t0], 0), NUMQ - 1);
        int ri = min(max(r_[b * SEQ + t0], 0), 1);
        float kf = k_emb[(size_t)qi * DD + lane];
        float vf = v_emb[(size_t)(qi + ri * NUMQ) * DD + lane];

        #pragma unroll
        for (int tt = 0; tt < CLEN; ++tt) {
            const int row = b * SEQ + t0 + tt;
            const float kcur = kf, vcur = vf;
            if (tt + 1 < CLEN) {               // prefetch stays inside chunk
                int qn = min(max(q_[row + 1], 0), NUMQ - 1);
                int rn = min(max(r_[row + 1], 0), 1);
                kf = k_emb[(size_t)qn * DD + lane];
                vf = v_emb[(size_t)(qn + rn * NUMQ) * DD + lane];
            }
            kv[lane]      = kcur;              // same-wave LDS write->read
            kv[64 + lane] = vcur;

            // softmax over all 50 m (lane = m)
            float s = 0.f;
            for (int dd = 0; dd < DD; ++dd)
                s = __builtin_fmaf(kv[dd], Mk_l[lane * 65 + dd], s);
            float mx = (lane < MM) ? s : -1e30f;
            #pragma unroll
            for (int off = 32; off >= 1; off >>= 1)
                mx = fmaxf(mx, __shfl_xor(mx, off, 64));
            float ex = (lane < MM) ? expf(s - mx) : 0.f;
            float sm = ex;
            #pragma unroll
            for (int off = 32; off >= 1; off >>= 1)
                sm += __shfl_xor(sm, off, 64);
            const float wm = ex / sm;          // valid lane<50; 0 for lane>=50
            if (lane >= mb && lane < mb + MH)
                WL[wv][tt][lane - mb] = wm;    // own half -> LDS (broadcast-read later)

            // e, a (lane = d)
            float ea = be_l, aa = ba_l;
            for (int dd = 0; dd < DD; ++dd) {
                const float vb = kv[64 + dd];
                ea = __builtin_fmaf(vb, We_l[dd * DD + lane], ea);
                aa = __builtin_fmaf(vb, Wa_l[dd * DD + lane], aa);
            }
            const float e_v = 1.f / (1.f + expf(-ea));
            const float a_v = tanhf(aa);
            e20[tt] = e_v;
            a20[tt] = a_v;

            // fold into affine summary (cell (mb+j, lane))
            #pragma unroll
            for (int j = 0; j < MH; ++j) {
                const float wj = rdlane(wm, mb + j);
                const float f  = __builtin_fmaf(-wj, e_v, 1.f);
                A[j] *= f;
                B[j] = __builtin_fmaf(B[j], f, wj * a_v);
            }
        }
    }
    __syncthreads();    // all waves done reading weights; POOL becomes S

    // ---- init S = Mv0; write Mv[b,0] plane slice ----
    float* outb = out_Mv + (size_t)b * (SEQ + 1) * MM * DD + (size_t)mb * DD;
    if (wv == 0) {
        #pragma unroll
        for (int j = 0; j < MH; ++j) {
            const float m0v = Mv0[(mb + j) * DD + lane];
            POOL[j * DD + lane] = m0v;
            outb[j * DD + lane] = m0v;
        }
    }
    __syncthreads();

    // ---- phase 2: serial handoff -> exact entry state per wave ----
    float Mv[MH];
    for (int w = 0; w < CHUNKS; ++w) {
        if (wv == w) {
            #pragma unroll
            for (int j = 0; j < MH; ++j) {
                Mv[j] = POOL[j * DD + lane];
                POOL[j * DD + lane] = __builtin_fmaf(A[j], Mv[j], B[j]);
            }
        }
        __syncthreads();
    }

    // ---- phase 3: replay from reg/LDS coefficients; LDS-staged float4 stores ----
    float* rrow = read2_buf + (size_t)(h * BATCH + b) * SEQ * DD;
    float* sp   = POOL + wv * (MH * DD);

    #pragma unroll
    for (int tt = 0; tt < CLEN; ++tt) {
        const int t = t0 + tt;
        const float e_v = e20[tt];
        const float a_v = a20[tt];
        float racc0 = 0.f, racc1 = 0.f;
        #pragma unroll
        for (int j = 0; j < MH; ++j) {
            const float wj    = WL[wv][tt][j];   // same-address broadcast read
            const float m_old = Mv[j];
            if (j & 1) racc1 = __builtin_fmaf(wj, m_old, racc1);
            else       racc0 = __builtin_fmaf(wj, m_old, racc0);
            Mv[j] = __builtin_fmaf(wj, __builtin_fmaf(-e_v, m_old, a_v), m_old);
            sp[j * DD + lane] = Mv[j];
        }
        float* outt = outb + (size_t)(t + 1) * MM * DD;
        #pragma unroll
        for (int k = 0; k < 7; ++k) {
            const int f = lane + 64 * k;
            if (f < MH * DD / 4) {
                const float4 v4 = *reinterpret_cast<const float4*>(&sp[4 * f]);
                *reinterpret_cast<float4*>(&outt[4 * f]) = v4;
            }
        }
        rrow[(size_t)t * DD + lane] = racc0 + racc1;
    }
}

// ---------------- K3': 256 blocks x 640 thr, 100 rows/block, Wf staged once ----------------
__global__ __launch_bounds__(640) void k3_block(
    const int* __restrict__ q,
    const float* __restrict__ k_emb,
    const float* __restrict__ read2_buf,
    const float* __restrict__ Wf, const float* __restrict__ bfb,
    const float* __restrict__ Wp, const float* __restrict__ bp,
    float* __restrict__ out_p)
{
    __shared__ float Wf_l[2 * DD][DD + 1];   // 33.3 KB
    __shared__ float RBUF[CHUNKS][128];

    const int tid  = threadIdx.x;
    const int wv   = tid >> 6;
    const int lane = tid & 63;

    for (int i = tid; i < 2 * DD * DD; i += 640)
        Wf_l[i >> 6][i & 63] = Wf[i];
    __syncthreads();

    const float bf_l = bfb[lane];
    const float wp_l = Wp[lane];
    const float bp0  = bp[0];
    const int row0 = blockIdx.x * 100 + wv * 10;

    const float* rd0 = read2_buf;
    const float* rd1 = read2_buf + (size_t)BATCH * SEQ * DD;
    float* rk = RBUF[wv];

    for (int i = 0; i < 10; ++i) {
        const int row = row0 + i;
        int qi = q[row];
        qi = min(max(qi, 0), NUMQ - 1);
        rk[lane]      = rd0[(size_t)row * DD + lane] + rd1[(size_t)row * DD + lane];
        rk[64 + lane] = k_emb[(size_t)qi * DD + lane];   // same-wave write->read

        float acc = bf_l;
        #pragma unroll
        for (int ii = 0; ii < 2 * DD; ++ii)
            acc = __builtin_fmaf(rk[ii], Wf_l[ii][lane], acc);
        const float f = tanhf(acc);

        float pv = f * wp_l;
        #pragma unroll
        for (int off = 32; off >= 1; off >>= 1)
            pv += __shfl_xor(pv, off, 64);
        if (lane == 0)
            out_p[row] = 1.f / (1.f + expf(-(pv + bp0)));
    }
}

// ---------------- Last-resort fallback: round-5 fused single kernel (proven, ws-free) ----------------
__global__ __launch_bounds__(640) void dkvmn_fused(
    const int* q_, const int* r_,
    const float* k_emb, const float* v_emb, const float* Mk, const float* Mv0,
    const float* We, const float* be, const float* Wa, const float* ba,
    const float* Wf, const float* bfb, const float* Wp, const float* bp,
    float* out_p, float* out_Mv)
{
    __shared__ float Mk_l[MM][DD + 1];
    __shared__ bf16  ring[SEQ][DD];
    __shared__ int   q_row[SEQ], x_row[SEQ];
    __shared__ float kbuf[DD], vbuf[DD], vbuf2[DD];
    __shared__ float wst[MM], est[DD], ast[DD];
    __shared__ float partial[640];
    __shared__ float bias_e[DD], bias_a[DD];

    const int b    = blockIdx.x;
    const int tid  = threadIdx.x;
    const int wv   = tid >> 6;
    const int lane = tid & 63;

    for (int t = tid; t < SEQ; t += 640) {
        int qi = q_[b * SEQ + t], ri = r_[b * SEQ + t];
        qi = min(max(qi, 0), NUMQ - 1); ri = min(max(ri, 0), 1);
        q_row[t] = qi; x_row[t] = qi + ri * NUMQ;
    }
    for (int i = tid; i < MM * DD; i += 640) Mk_l[i >> 6][i & 63] = Mk[i];
    if (tid < DD) { bias_e[tid] = be[tid]; bias_a[tid] = ba[tid]; }

    const int d  = lane;
    const int m0 = wv * 5;
    float* outb = out_Mv + (size_t)b * (SEQ + 1) * MM * DD;
    float Mv[5];
    #pragma unroll
    for (int j = 0; j < 5; ++j) {
        Mv[j] = Mv0[(m0 + j) * DD + d];
        outb[(m0 + j) * DD + d] = Mv[j];
    }
    __syncthreads();

    float kf_n = 0.f, vf_n = 0.f, vf2_n = 0.f;
    if (wv == 0) kf_n  = k_emb[(size_t)q_row[0] * DD + lane];
    if (wv == 1) vf_n  = v_emb[(size_t)x_row[0] * DD + lane];
    if (wv == 2) vf2_n = v_emb[(size_t)x_row[0] * DD + lane];

    for (int t = 0; t < SEQ; ++t) {
        if (wv == 0) {
            kbuf[lane] = kf_n;
            if (t + 1 < SEQ) kf_n = k_emb[(size_t)q_row[t + 1] * DD + lane];
            float s = 0.f;
            if (lane < MM) {
                #pragma unroll
                for (int dd = 0; dd < DD; ++dd) s += kbuf[dd] * Mk_l[lane][dd];
            }
            float mx = (lane < MM) ? s : -1e30f;
            #pragma unroll
            for (int off = 32; off >= 1; off >>= 1) mx = fmaxf(mx, __shfl_xor(mx, off, 64));
            float ex = (lane < MM) ? expf(s - mx) : 0.f;
            float sm = ex;
            #pragma unroll
            for (int off = 32; off >= 1; off >>= 1) sm += __shfl_xor(sm, off, 64);
            if (lane < MM) wst[lane] = ex / sm;
        } else if (wv == 1) {
            vbuf[lane] = vf_n;
            if (t + 1 < SEQ) vf_n = v_emb[(size_t)x_row[t + 1] * DD + lane];
            float acc = bias_e[lane];
            #pragma unroll
            for (int dd = 0; dd < DD; ++dd) acc += vbuf[dd] * We[dd * DD + lane];
            est[lane] = 1.f / (1.f + expf(-acc));
        } else if (wv == 2) {
            vbuf2[lane] = vf2_n;
            if (t + 1 < SEQ) vf2_n = v_emb[(size_t)x_row[t + 1] * DD + lane];
            float acc = bias_a[lane];
            #pragma unroll
            for (int dd = 0; dd < DD; ++dd) acc += vbuf2[dd] * Wa[dd * DD + lane];
            ast[lane] = tanhf(acc);
        }
        __syncthreads();

        const float e_v = est[d];
        const float a_v = ast[d];
        float racc = 0.f;
        float* outt = outb + (size_t)(t + 1) * MM * DD;
        #pragma unroll
        for (int j = 0; j < 5; ++j) {
            const float wvv = wst[m0 + j];
            racc += wvv * Mv[j];
            Mv[j] = __builtin_fmaf(wvv, a_v - e_v * Mv[j], Mv[j]);
            outt[(m0 + j) * DD + d] = Mv[j];
        }
        partial[tid] = racc;
        __syncthreads();

        if (tid < DD) {
            float rr = 0.f;
            #pragma unroll
            for (int g = 0; g < 10; ++g) rr += partial[g * 64 + tid];
            ring[t][tid] = (bf16)rr;
        }
    }
    __syncthreads();

    for (int t = wv; t < SEQ; t += 10) {
        const int qi = q_row[t];
        const float kreg = k_emb[(size_t)qi * DD + lane];
        float acc = bfb[lane];
        #pragma unroll
        for (int i = 0; i < DD; ++i) acc += (float)ring[t][i] * Wf[i * DD + lane];
        #pragma unroll
        for (int i = 0; i < DD; ++i) acc += __shfl(kreg, i, 64) * Wf[(DD + i) * DD + lane];
        const float f = tanhf(acc);
        float pv = f * Wp[lane];
        #pragma unroll
        for (int off = 32; off >= 1; off >>= 1) pv += __shfl_xor(pv, off, 64);
        if (lane == 0)
            out_p[(size_t)b * SEQ + t] = 1.f / (1.f + expf(-(pv + bp[0])));
    }
}

extern "C" void kernel_launch(void* const* d_in, const int* in_sizes, int n_in,
                              void* d_out, int out_size, void* d_ws, size_t ws_size,
                              hipStream_t stream) {
    const int*   q     = (const int*)  d_in[0];
    const int*   r     = (const int*)  d_in[1];
    const float* k_emb = (const float*)d_in[4];
    const float* v_emb = (const float*)d_in[5];
    const float* Mk    = (const float*)d_in[6];
    const float* Mv0   = (const float*)d_in[7];
    const float* We    = (const float*)d_in[8];
    const float* be    = (const float*)d_in[9];
    const float* Wa    = (const float*)d_in[10];
    const float* ba    = (const float*)d_in[11];
    const float* Wf    = (const float*)d_in[12];
    const float* bfb   = (const float*)d_in[13];
    const float* Wp    = (const float*)d_in[14];
    const float* bp    = (const float*)d_in[15];

    float* out_p  = (float*)d_out;                 // [128,200]
    float* out_Mv = (float*)d_out + BATCH * SEQ;   // [128,201,50,64]

    const size_t N_D = (size_t)BATCH * SEQ * DD;
    const size_t WS_NEEDED = 2 * N_D * sizeof(float);   // read2 only, ~26.2 MB

    if (ws_size >= WS_NEEDED) {
        float* read2_buf = (float*)d_ws;            // [2,B,SEQ,64]

        hipLaunchKernelGGL(k2_fused0, dim3(BATCH * 2), dim3(640), 0, stream,
                           q, r, k_emb, v_emb, Mk, Mv0, We, be, Wa, ba,
                           read2_buf, out_Mv);
        hipLaunchKernelGGL(k3_block, dim3(BATCH * SEQ / 100), dim3(640), 0, stream,
                           q, k_emb, read2_buf, Wf, bfb, Wp, bp, out_p);
    } else {
        hipLaunchKernelGGL(dkvmn_fused, dim3(BATCH), dim3(640), 0, stream,
                           q, r, k_emb, v_emb, Mk, Mv0, We, be, Wa, ba,
                           Wf, bfb, Wp, bp, out_p, out_Mv);
    }
}

// Round 20
// 158.215 us; speedup vs baseline: 6.6220x; 6.6220x over previous
//
#include <hip/hip_runtime.h>
#include <hip/hip_bf16.h>

typedef __hip_bfloat16 bf16;

#define BATCH 128
#define SEQ   200
#define NUMQ  1000
#define DD    64
#define MM    50
#define MH    25     // m-half
#define CHUNKS 10
#define CLEN   20    // SEQ / CHUNKS

// Budget (measured r16/r18): fixed ~14, K2 body ~72 (near store floor), gaps ~8.
// r19 lesson: phase-0 fusion spills regs -> scratch (3.4GB traffic). This round:
// keep proven k2_hier; reshape K1/K3 to 256 blocks x 640 thr staging weights ONCE
// (r18-phase-A shape / r19 k3_block, both correctness-proven).

__device__ __forceinline__ float rdlane(float v, int j) {
    return __uint_as_float(__builtin_amdgcn_readlane(__float_as_uint(v), j));
}

// ---------------- K1: 256 blocks x 640 thr, 100 rows/block, weights staged once ----------------
__global__ __launch_bounds__(640) void k1_block(
    const int* __restrict__ q, const int* __restrict__ r,
    const float* __restrict__ k_emb, const float* __restrict__ v_emb,
    const float* __restrict__ Mk,
    const float* __restrict__ We, const float* __restrict__ be,
    const float* __restrict__ Wa, const float* __restrict__ ba,
    float* __restrict__ w_buf, float* __restrict__ e_buf, float* __restrict__ a_buf)
{
    __shared__ float Mk_l[MM * 65];       // [50][65]
    __shared__ float We_l[DD * DD];       // [64][64]
    __shared__ float Wa_l[DD * DD];
    __shared__ float RBUF[CHUNKS][128];   // per-wave k/v row

    const int tid  = threadIdx.x;
    const int wv   = tid >> 6;
    const int lane = tid & 63;

    for (int i = tid; i < MM * DD; i += 640) Mk_l[(i >> 6) * 65 + (i & 63)] = Mk[i];
    for (int i = tid; i < DD * DD; i += 640) { We_l[i] = We[i]; Wa_l[i] = Wa[i]; }
    const float be_l = be[lane];
    const float ba_l = ba[lane];
    __syncthreads();

    const int row0 = blockIdx.x * 100 + wv * 10;   // 256 blocks x 10 waves x 10 rows
    float* kv = RBUF[wv];

    int qi = min(max(q[row0], 0), NUMQ - 1);
    int ri = min(max(r[row0], 0), 1);
    float kf = k_emb[(size_t)qi * DD + lane];
    float vf = v_emb[(size_t)(qi + ri * NUMQ) * DD + lane];

    for (int i = 0; i < 10; ++i) {
        const int row = row0 + i;
        const float kcur = kf, vcur = vf;
        if (i + 1 < 10) {                  // prefetch next row's gathers
            int qn = min(max(q[row + 1], 0), NUMQ - 1);
            int rn = min(max(r[row + 1], 0), 1);
            kf = k_emb[(size_t)qn * DD + lane];
            vf = v_emb[(size_t)(qn + rn * NUMQ) * DD + lane];
        }
        kv[lane]      = kcur;              // same-wave LDS write->read (in-order)
        kv[64 + lane] = vcur;

        // softmax over m (lane = m)
        float s = 0.f;
        if (lane < MM) {
            #pragma unroll
            for (int dd = 0; dd < DD; ++dd)
                s = __builtin_fmaf(kv[dd], Mk_l[lane * 65 + dd], s);
        }
        float mx = (lane < MM) ? s : -1e30f;
        #pragma unroll
        for (int off = 32; off >= 1; off >>= 1)
            mx = fmaxf(mx, __shfl_xor(mx, off, 64));
        float ex = (lane < MM) ? expf(s - mx) : 0.f;
        float sm = ex;
        #pragma unroll
        for (int off = 32; off >= 1; off >>= 1)
            sm += __shfl_xor(sm, off, 64);
        if (lane < MM)
            w_buf[(size_t)row * MM + lane] = ex / sm;

        // e, a (lane = d)
        float ea = be_l, aa = ba_l;
        #pragma unroll
        for (int dd = 0; dd < DD; ++dd) {
            const float vb = kv[64 + dd];
            ea = __builtin_fmaf(vb, We_l[dd * DD + lane], ea);
            aa = __builtin_fmaf(vb, Wa_l[dd * DD + lane], aa);
        }
        e_buf[(size_t)row * DD + lane] = 1.f / (1.f + expf(-ea));
        a_buf[(size_t)row * DD + lane] = tanhf(aa);
    }
}

// ---------------- K2: r13/r15 hierarchical in-block scan (verbatim, best measured) ----------------
__global__ __launch_bounds__(640) void k2_hier(
    const float* __restrict__ Mv0,
    const float* __restrict__ w_buf, const float* __restrict__ e_buf,
    const float* __restrict__ a_buf,
    float* __restrict__ read2_buf, float* __restrict__ out_Mv)
{
    __shared__ float POOL[CHUNKS * MH * DD];   // 64 KB

    const int blk  = blockIdx.x;
    const int b    = blk >> 1;
    const int h    = blk & 1;
    const int tid  = threadIdx.x;
    const int wv   = tid >> 6;
    const int lane = tid & 63;
    const int t0   = wv * CLEN;
    const int mb   = h * MH;

    const float* wrow = w_buf + (size_t)b * SEQ * MM + mb;
    const float* erow = e_buf + (size_t)b * SEQ * DD;
    const float* arow = a_buf + (size_t)b * SEQ * DD;

    float A[MH], B[MH];
    #pragma unroll
    for (int j = 0; j < MH; ++j) { A[j] = 1.f; B[j] = 0.f; }

    float wreg = (lane < MH) ? wrow[(size_t)t0 * MM + lane] : 0.f;
    float e_n  = erow[(size_t)t0 * DD + lane];
    float a_n  = arow[(size_t)t0 * DD + lane];

    for (int tt = 0; tt < CLEN; ++tt) {
        const int t = t0 + tt;
        const float e_v = e_n, a_v = a_n, wcur = wreg;
        if (t + 1 < SEQ) {
            wreg = (lane < MH) ? wrow[(size_t)(t + 1) * MM + lane] : 0.f;
            e_n  = erow[(size_t)(t + 1) * DD + lane];
            a_n  = arow[(size_t)(t + 1) * DD + lane];
        }
        #pragma unroll
        for (int j = 0; j < MH; ++j) {
            const float wj = rdlane(wcur, j);
            const float f  = __builtin_fmaf(-wj, e_v, 1.f);
            A[j] *= f;
            B[j] = __builtin_fmaf(B[j], f, wj * a_v);
        }
    }

    float* outb = out_Mv + (size_t)b * (SEQ + 1) * MM * DD + (size_t)mb * DD;
    if (wv == 0) {
        #pragma unroll
        for (int j = 0; j < MH; ++j) {
            const float m0v = Mv0[(mb + j) * DD + lane];
            POOL[j * DD + lane] = m0v;
            outb[j * DD + lane] = m0v;
        }
    }
    __syncthreads();

    float Mv[MH];
    for (int w = 0; w < CHUNKS; ++w) {
        if (wv == w) {
            #pragma unroll
            for (int j = 0; j < MH; ++j) {
                Mv[j] = POOL[j * DD + lane];
                POOL[j * DD + lane] = __builtin_fmaf(A[j], Mv[j], B[j]);
            }
        }
        __syncthreads();
    }

    float* rrow = read2_buf + ((size_t)h * BATCH + b) * SEQ * DD;
    float* sp   = POOL + wv * (MH * DD);

    wreg = (lane < MH) ? wrow[(size_t)t0 * MM + lane] : 0.f;
    e_n  = erow[(size_t)t0 * DD + lane];
    a_n  = arow[(size_t)t0 * DD + lane];

    for (int tt = 0; tt < CLEN; ++tt) {
        const int t = t0 + tt;
        const float e_v = e_n, a_v = a_n, wcur = wreg;
        if (t + 1 < SEQ) {
            wreg = (lane < MH) ? wrow[(size_t)(t + 1) * MM + lane] : 0.f;
            e_n  = erow[(size_t)(t + 1) * DD + lane];
            a_n  = arow[(size_t)(t + 1) * DD + lane];
        }
        float racc0 = 0.f, racc1 = 0.f;
        #pragma unroll
        for (int j = 0; j < MH; ++j) {
            const float wj    = rdlane(wcur, j);
            const float m_old = Mv[j];
            if (j & 1) racc1 = __builtin_fmaf(wj, m_old, racc1);
            else       racc0 = __builtin_fmaf(wj, m_old, racc0);
            Mv[j] = __builtin_fmaf(wj, __builtin_fmaf(-e_v, m_old, a_v), m_old);
            sp[j * DD + lane] = Mv[j];
        }
        float* outt = outb + (size_t)(t + 1) * MM * DD;
        #pragma unroll
        for (int k = 0; k < 7; ++k) {
            const int f = lane + 64 * k;
            if (f < MH * DD / 4) {
                const float4 v4 = *reinterpret_cast<const float4*>(&sp[4 * f]);
                *reinterpret_cast<float4*>(&outt[4 * f]) = v4;
            }
        }
        rrow[(size_t)t * DD + lane] = racc0 + racc1;
    }
}

// ---------------- K3: 256 blocks x 640 thr, 100 rows/block, Wf staged once (r19-proven) ----------------
__global__ __launch_bounds__(640) void k3_block(
    const int* __restrict__ q,
    const float* __restrict__ k_emb,
    const float* __restrict__ read2_buf,
    const float* __restrict__ Wf, const float* __restrict__ bfb,
    const float* __restrict__ Wp, const float* __restrict__ bp,
    float* __restrict__ out_p)
{
    __shared__ float Wf_l[2 * DD][DD + 1];   // 33.3 KB
    __shared__ float RBUF[CHUNKS][128];

    const int tid  = threadIdx.x;
    const int wv   = tid >> 6;
    const int lane = tid & 63;

    for (int i = tid; i < 2 * DD * DD; i += 640)
        Wf_l[i >> 6][i & 63] = Wf[i];
    __syncthreads();

    const float bf_l = bfb[lane];
    const float wp_l = Wp[lane];
    const float bp0  = bp[0];
    const int row0 = blockIdx.x * 100 + wv * 10;

    const float* rd0 = read2_buf;
    const float* rd1 = read2_buf + (size_t)BATCH * SEQ * DD;
    float* rk = RBUF[wv];

    for (int i = 0; i < 10; ++i) {
        const int row = row0 + i;
        int qi = q[row];
        qi = min(max(qi, 0), NUMQ - 1);
        rk[lane]      = rd0[(size_t)row * DD + lane] + rd1[(size_t)row * DD + lane];
        rk[64 + lane] = k_emb[(size_t)qi * DD + lane];   // same-wave write->read

        float acc = bf_l;
        #pragma unroll
        for (int ii = 0; ii < 2 * DD; ++ii)
            acc = __builtin_fmaf(rk[ii], Wf_l[ii][lane], acc);
        const float f = tanhf(acc);

        float pv = f * wp_l;
        #pragma unroll
        for (int off = 32; off >= 1; off >>= 1)
            pv += __shfl_xor(pv, off, 64);
        if (lane == 0)
            out_p[row] = 1.f / (1.f + expf(-(pv + bp0)));
    }
}

// ---------------- Last-resort fallback: round-5 fused single kernel (proven, ws-free) ----------------
__global__ __launch_bounds__(640) void dkvmn_fused(
    const int* q_, const int* r_,
    const float* k_emb, const float* v_emb, const float* Mk, const float* Mv0,
    const float* We, const float* be, const float* Wa, const float* ba,
    const float* Wf, const float* bfb, const float* Wp, const float* bp,
    float* out_p, float* out_Mv)
{
    __shared__ float Mk_l[MM][DD + 1];
    __shared__ bf16  ring[SEQ][DD];
    __shared__ int   q_row[SEQ], x_row[SEQ];
    __shared__ float kbuf[DD], vbuf[DD], vbuf2[DD];
    __shared__ float wst[MM], est[DD], ast[DD];
    __shared__ float partial[640];
    __shared__ float bias_e[DD], bias_a[DD];

    const int b    = blockIdx.x;
    const int tid  = threadIdx.x;
    const int wv   = tid >> 6;
    const int lane = tid & 63;

    for (int t = tid; t < SEQ; t += 640) {
        int qi = q_[b * SEQ + t], ri = r_[b * SEQ + t];
        qi = min(max(qi, 0), NUMQ - 1); ri = min(max(ri, 0), 1);
        q_row[t] = qi; x_row[t] = qi + ri * NUMQ;
    }
    for (int i = tid; i < MM * DD; i += 640) Mk_l[i >> 6][i & 63] = Mk[i];
    if (tid < DD) { bias_e[tid] = be[tid]; bias_a[tid] = ba[tid]; }

    const int d  = lane;
    const int m0 = wv * 5;
    float* outb = out_Mv + (size_t)b * (SEQ + 1) * MM * DD;
    float Mv[5];
    #pragma unroll
    for (int j = 0; j < 5; ++j) {
        Mv[j] = Mv0[(m0 + j) * DD + d];
        outb[(m0 + j) * DD + d] = Mv[j];
    }
    __syncthreads();

    float kf_n = 0.f, vf_n = 0.f, vf2_n = 0.f;
    if (wv == 0) kf_n  = k_emb[(size_t)q_row[0] * DD + lane];
    if (wv == 1) vf_n  = v_emb[(size_t)x_row[0] * DD + lane];
    if (wv == 2) vf2_n = v_emb[(size_t)x_row[0] * DD + lane];

    for (int t = 0; t < SEQ; ++t) {
        if (wv == 0) {
            kbuf[lane] = kf_n;
            if (t + 1 < SEQ) kf_n = k_emb[(size_t)q_row[t + 1] * DD + lane];
            float s = 0.f;
            if (lane < MM) {
                #pragma unroll
                for (int dd = 0; dd < DD; ++dd) s += kbuf[dd] * Mk_l[lane][dd];
            }
            float mx = (lane < MM) ? s : -1e30f;
            #pragma unroll
            for (int off = 32; off >= 1; off >>= 1) mx = fmaxf(mx, __shfl_xor(mx, off, 64));
            float ex = (lane < MM) ? expf(s - mx) : 0.f;
            float sm = ex;
            #pragma unroll
            for (int off = 32; off >= 1; off >>= 1) sm += __shfl_xor(sm, off, 64);
            if (lane < MM) wst[lane] = ex / sm;
        } else if (wv == 1) {
            vbuf[lane] = vf_n;
            if (t + 1 < SEQ) vf_n = v_emb[(size_t)x_row[t + 1] * DD + lane];
            float acc = bias_e[lane];
            #pragma unroll
            for (int dd = 0; dd < DD; ++dd) acc += vbuf[dd] * We[dd * DD + lane];
            est[lane] = 1.f / (1.f + expf(-acc));
        } else if (wv == 2) {
            vbuf2[lane] = vf2_n;
            if (t + 1 < SEQ) vf2_n = v_emb[(size_t)x_row[t + 1] * DD + lane];
            float acc = bias_a[lane];
            #pragma unroll
            for (int dd = 0; dd < DD; ++dd) acc += vbuf2[dd] * Wa[dd * DD + lane];
            ast[lane] = tanhf(acc);
        }
        __syncthreads();

        const float e_v = est[d];
        const float a_v = ast[d];
        float racc = 0.f;
        float* outt = outb + (size_t)(t + 1) * MM * DD;
        #pragma unroll
        for (int j = 0; j < 5; ++j) {
            const float wvv = wst[m0 + j];
            racc += wvv * Mv[j];
            Mv[j] = __builtin_fmaf(wvv, a_v - e_v * Mv[j], Mv[j]);
            outt[(m0 + j) * DD + d] = Mv[j];
        }
        partial[tid] = racc;
        __syncthreads();

        if (tid < DD) {
            float rr = 0.f;
            #pragma unroll
            for (int g = 0; g < 10; ++g) rr += partial[g * 64 + tid];
            ring[t][tid] = (bf16)rr;
        }
    }
    __syncthreads();

    for (int t = wv; t < SEQ; t += 10) {
        const int qi = q_row[t];
        const float kreg = k_emb[(size_t)qi * DD + lane];
        float acc = bfb[lane];
        #pragma unroll
        for (int i = 0; i < DD; ++i) acc += (float)ring[t][i] * Wf[i * DD + lane];
        #pragma unroll
        for (int i = 0; i < DD; ++i) acc += __shfl(kreg, i, 64) * Wf[(DD + i) * DD + lane];
        const float f = tanhf(acc);
        float pv = f * Wp[lane];
        #pragma unroll
        for (int off = 32; off >= 1; off >>= 1) pv += __shfl_xor(pv, off, 64);
        if (lane == 0)
            out_p[(size_t)b * SEQ + t] = 1.f / (1.f + expf(-(pv + bp[0])));
    }
}

extern "C" void kernel_launch(void* const* d_in, const int* in_sizes, int n_in,
                              void* d_out, int out_size, void* d_ws, size_t ws_size,
                              hipStream_t stream) {
    const int*   q     = (const int*)  d_in[0];
    const int*   r     = (const int*)  d_in[1];
    const float* k_emb = (const float*)d_in[4];
    const float* v_emb = (const float*)d_in[5];
    const float* Mk    = (const float*)d_in[6];
    const float* Mv0   = (const float*)d_in[7];
    const float* We    = (const float*)d_in[8];
    const float* be    = (const float*)d_in[9];
    const float* Wa    = (const float*)d_in[10];
    const float* ba    = (const float*)d_in[11];
    const float* Wf    = (const float*)d_in[12];
    const float* bfb   = (const float*)d_in[13];
    const float* Wp    = (const float*)d_in[14];
    const float* bp    = (const float*)d_in[15];

    float* out_p  = (float*)d_out;                 // [128,200]
    float* out_Mv = (float*)d_out + BATCH * SEQ;   // [128,201,50,64]

    const size_t N_W  = (size_t)BATCH * SEQ * MM;      // w
    const size_t N_D  = (size_t)BATCH * SEQ * DD;      // e / a / read-half
    const size_t WS_NEEDED = (N_W + 4 * N_D) * sizeof(float);   // ~31.3 MB

    if (ws_size >= WS_NEEDED) {
        float* w_buf     = (float*)d_ws;           // [B,SEQ,50]
        float* e_buf     = w_buf + N_W;            // [B,SEQ,64]
        float* a_buf     = e_buf + N_D;            // [B,SEQ,64]
        float* read2_buf = a_buf + N_D;            // [2,B,SEQ,64]

        hipLaunchKernelGGL(k1_block, dim3(BATCH * SEQ / 100), dim3(640), 0, stream,
                           q, r, k_emb, v_emb, Mk, We, be, Wa, ba,
                           w_buf, e_buf, a_buf);
        hipLaunchKernelGGL(k2_hier, dim3(BATCH * 2), dim3(640), 0, stream,
                           Mv0, w_buf, e_buf, a_buf, read2_buf, out_Mv);
        hipLaunchKernelGGL(k3_block, dim3(BATCH * SEQ / 100), dim3(640), 0, stream,
                           q, k_emb, read2_buf, Wf, bfb, Wp, bp, out_p);
    } else {
        hipLaunchKernelGGL(dkvmn_fused, dim3(BATCH), dim3(640), 0, stream,
                           q, r, k_emb, v_emb, Mk, Mv0, We, be, Wa, ba,
                           Wf, bfb, Wp, bp, out_p, out_Mv);
    }
}